// Round 8
// baseline (192.221 us; speedup 1.0000x reference)
//
#include <hip/hip_runtime.h>
#include <math.h>

// GCN 2-layer, algebraically fused, no global FP atomics:
//   agg_x[d] = dinv[d]*(sum_{s in N(d)} xp[s] + xp[d]),  xp = dinv*x
//   h = relu(agg_x@W1+b1); g = h@W2; gp = dinv*g
//   out = log_softmax(dinv[d]*(sum gp[s] + gp[d]) + b2)
//
// R2: bucketed counting sort (256 nodes/bucket) + per-bucket LDS aggregation.
// R3: parallel scan.  R4: 8-way sliced agg, premultiplied dinv, staged scatter.
// R5: stage_b[], shuffle scans, int4 loads.  R6: SoA LDS acc (neutral).
// R7: hist+scan_col+scan_tot+scatter fused into ONE k_sort kernel:
//     fixed-capacity bucket regions (CAP=9216 = mean+11sigma), space reserved
//     via global atomic cursors (line-padded, 1 atomic per tile-bucket pair).
//     Intra-bucket order is nondeterministic — aggregation sums don't care.
//     Kills 3 dispatches + table traffic; bkt_off replaced by cursor counts.

#define BLK 256
#define NTILE 512
#define EPTMAX 6400        // >= runtime ept (6252), multiple of 4
#define MAXB 512           // >= nbkt = 391
#define NS 8               // slices per bucket in Phase B
#define CAP 9216           // bucket region capacity (mean 8192, sd ~90)
#define GSTRIDE 16         // ints per cursor (64B line padding)

// ---------- Phase A: fused hist + reserve + staged scatter ----------
__global__ void k_sort(const int* __restrict__ src, const int* __restrict__ dst,
                       int* __restrict__ gcur, unsigned* __restrict__ sorted,
                       int e, int ept, int nbkt) {
    __shared__ int h[MAXB];
    __shared__ int cur[MAXB];
    __shared__ int base2[MAXB];
    __shared__ unsigned stage[EPTMAX];
    __shared__ unsigned short stage_b[EPTMAX];
    __shared__ int wpart[BLK / 64];
    int tile = blockIdx.x;
    int t = threadIdx.x;
    int lo = tile * ept;
    int hi = min(lo + ept, e);
    int total = hi - lo;

    // pass 1: LDS histogram of bucket counts
    h[t] = 0; h[t + BLK] = 0;
    __syncthreads();
    for (int i = lo + 4 * t; i < hi; i += 4 * BLK) {
        int4 d4 = *(const int4*)(dst + i);
        atomicAdd(&h[d4.x >> 8], 1);
        atomicAdd(&h[d4.y >> 8], 1);
        atomicAdd(&h[d4.z >> 8], 1);
        atomicAdd(&h[d4.w >> 8], 1);
    }
    __syncthreads();

    // local exclusive offsets via pair shuffle scan; reserve global space
    int b0 = 2 * t, b1 = 2 * t + 1;
    int c0 = h[b0], c1 = h[b1];
    int p = c0 + c1;
    int x = p;
    int lane = t & 63;
#pragma unroll
    for (int ofs = 1; ofs < 64; ofs <<= 1) {
        int y = __shfl_up(x, ofs, 64);
        if (lane >= ofs) x += y;
    }
    if (lane == 63) wpart[t >> 6] = x;
    __syncthreads();
    if (t < BLK / 64) {
        int s = wpart[t];
        int w = s;
#pragma unroll
        for (int ofs = 1; ofs < BLK / 64; ofs <<= 1) {
            int y = __shfl_up(w, ofs, 64);
            if (t >= ofs) w += y;
        }
        wpart[t] = w - s;
    }
    __syncthreads();
    int E = x + wpart[t >> 6] - p;     // exclusive local offset of bucket b0
    // reserve [g, g+c) in bucket region via global atomic cursor
    int g0 = 0, g1 = 0;
    if (c0 > 0) {
        g0 = atomicAdd(&gcur[b0 * GSTRIDE], c0);
        if (g0 + c0 > CAP) g0 = CAP - c0;   // safety clamp (P ~ 1e-24)
    }
    if (c1 > 0) {
        g1 = atomicAdd(&gcur[b1 * GSTRIDE], c1);
        if (g1 + c1 > CAP) g1 = CAP - c1;
    }
    cur[b0] = E;
    cur[b1] = E + c0;
    base2[b0] = b0 * CAP + g0 - E;
    base2[b1] = b1 * CAP + g1 - (E + c0);
    __syncthreads();

    // pass 2: place records into LDS stage in bucket order
    for (int i = lo + 4 * t; i < hi; i += 4 * BLK) {
        int4 s4 = *(const int4*)(src + i);
        int4 d4 = *(const int4*)(dst + i);
        int b, pos;
        b = d4.x >> 8; pos = atomicAdd(&cur[b], 1);
        stage[pos] = (unsigned)s4.x | ((unsigned)(d4.x & 255) << 17); stage_b[pos] = (unsigned short)b;
        b = d4.y >> 8; pos = atomicAdd(&cur[b], 1);
        stage[pos] = (unsigned)s4.y | ((unsigned)(d4.y & 255) << 17); stage_b[pos] = (unsigned short)b;
        b = d4.z >> 8; pos = atomicAdd(&cur[b], 1);
        stage[pos] = (unsigned)s4.z | ((unsigned)(d4.z & 255) << 17); stage_b[pos] = (unsigned short)b;
        b = d4.w >> 8; pos = atomicAdd(&cur[b], 1);
        stage[pos] = (unsigned)s4.w | ((unsigned)(d4.w & 255) << 17); stage_b[pos] = (unsigned short)b;
    }
    __syncthreads();
    // pass 3: bucket-contiguous global writes
    for (int j = t; j < total; j += BLK) {
        int b = stage_b[j];
        sorted[base2[b] + j] = stage[j];
    }
}

// ---------- degree ----------

__global__ void k_deg_slice(const unsigned* __restrict__ sorted, const int* __restrict__ gcur,
                            int* __restrict__ pdeg) {
    __shared__ int cnt[256];
    int b = blockIdx.x, s = blockIdx.y;
    cnt[threadIdx.x] = 0;
    __syncthreads();
    int lo = b * CAP;
    int len = gcur[b * GSTRIDE];
    int slo = lo + (int)((long long)len * s / NS);
    int shi = lo + (int)((long long)len * (s + 1) / NS);
    for (int i = slo + threadIdx.x; i < shi; i += 4 * BLK) {
        int i1 = i + BLK, i2 = i + 2 * BLK, i3 = i + 3 * BLK;
        unsigned p0 = sorted[i];
        unsigned p1 = (i1 < shi) ? sorted[i1] : 0;
        unsigned p2 = (i2 < shi) ? sorted[i2] : 0;
        unsigned p3 = (i3 < shi) ? sorted[i3] : 0;
        atomicAdd(&cnt[p0 >> 17], 1);
        if (i1 < shi) atomicAdd(&cnt[p1 >> 17], 1);
        if (i2 < shi) atomicAdd(&cnt[p2 >> 17], 1);
        if (i3 < shi) atomicAdd(&cnt[p3 >> 17], 1);
    }
    __syncthreads();
    pdeg[(b * NS + s) * 256 + threadIdx.x] = cnt[threadIdx.x];
}

__global__ void k_dinv_merge(const int* __restrict__ pdeg, const float* __restrict__ x,
                             float* __restrict__ dinv, float* __restrict__ xp, int n) {
    int i = blockIdx.x * BLK + threadIdx.x;
    if (i >= n) return;
    int b = i >> 8, t = i & 255;
    int deg = 1;  // self loop
#pragma unroll
    for (int s = 0; s < NS; ++s) deg += pdeg[(b * NS + s) * 256 + t];
    float d = rsqrtf((float)deg);
    dinv[i] = d;
    float2 xv = ((const float2*)x)[i];
    ((float2*)xp)[i] = make_float2(d * xv.x, d * xv.y);
}

// ---------- Phase B: sliced aggregation, SoA accumulators ----------

__global__ void k_agg_slice(const unsigned* __restrict__ sorted, const int* __restrict__ gcur,
                            const float* __restrict__ featp, float* __restrict__ partial) {
    __shared__ float accx[256];
    __shared__ float accy[256];
    int b = blockIdx.x, s = blockIdx.y;
    accx[threadIdx.x] = 0.f;
    accy[threadIdx.x] = 0.f;
    __syncthreads();
    int lo = b * CAP;
    int len = gcur[b * GSTRIDE];
    int slo = lo + (int)((long long)len * s / NS);
    int shi = lo + (int)((long long)len * (s + 1) / NS);
    for (int i = slo + threadIdx.x; i < shi; i += 4 * BLK) {
        int i1 = i + BLK, i2 = i + 2 * BLK, i3 = i + 3 * BLK;
        unsigned p0 = sorted[i];
        unsigned p1 = (i1 < shi) ? sorted[i1] : 0;
        unsigned p2 = (i2 < shi) ? sorted[i2] : 0;
        unsigned p3 = (i3 < shi) ? sorted[i3] : 0;
        float2 f0 = ((const float2*)featp)[p0 & 0x1FFFFu];
        float2 f1 = ((const float2*)featp)[p1 & 0x1FFFFu];
        float2 f2 = ((const float2*)featp)[p2 & 0x1FFFFu];
        float2 f3 = ((const float2*)featp)[p3 & 0x1FFFFu];
        atomicAdd(&accx[p0 >> 17], f0.x);
        atomicAdd(&accy[p0 >> 17], f0.y);
        if (i1 < shi) { atomicAdd(&accx[p1 >> 17], f1.x); atomicAdd(&accy[p1 >> 17], f1.y); }
        if (i2 < shi) { atomicAdd(&accx[p2 >> 17], f2.x); atomicAdd(&accy[p2 >> 17], f2.y); }
        if (i3 < shi) { atomicAdd(&accx[p3 >> 17], f3.x); atomicAdd(&accy[p3 >> 17], f3.y); }
    }
    __syncthreads();
    float* P = &partial[(size_t)(b * NS + s) * 512];
    P[threadIdx.x]       = accx[threadIdx.x];
    P[256 + threadIdx.x] = accy[threadIdx.x];
}

__global__ void k_mlp_merge(const float* __restrict__ partial, const float* __restrict__ dinv,
                            const float* __restrict__ xp,
                            const float* __restrict__ W1, const float* __restrict__ b1,
                            const float* __restrict__ W2, float* __restrict__ gp, int n) {
    int i = blockIdx.x * BLK + threadIdx.x;
    if (i >= n) return;
    int b = i >> 8, t = i & 255;
    float2 xv = ((const float2*)xp)[i];
    float ax = xv.x, ay = xv.y;
#pragma unroll
    for (int s = 0; s < NS; ++s) {
        const float* P = &partial[(size_t)(b * NS + s) * 512];
        ax += P[t]; ay += P[256 + t];
    }
    float d = dinv[i];
    ax *= d; ay *= d;
    float g0 = 0.f, g1 = 0.f;
#pragma unroll
    for (int f = 0; f < 16; ++f) {
        float h = fmaf(ax, W1[f], fmaf(ay, W1[16 + f], b1[f]));
        h = fmaxf(h, 0.0f);
        g0 = fmaf(h, W2[2 * f + 0], g0);
        g1 = fmaf(h, W2[2 * f + 1], g1);
    }
    ((float2*)gp)[i] = make_float2(d * g0, d * g1);
}

__global__ void k_final(const float* __restrict__ partial, const float* __restrict__ dinv,
                        const float* __restrict__ gp, const float* __restrict__ b2,
                        float* __restrict__ out, int n) {
    int i = blockIdx.x * BLK + threadIdx.x;
    if (i >= n) return;
    int b = i >> 8, t = i & 255;
    float2 gv = ((const float2*)gp)[i];
    float ax = gv.x, ay = gv.y;
#pragma unroll
    for (int s = 0; s < NS; ++s) {
        const float* P = &partial[(size_t)(b * NS + s) * 512];
        ax += P[t]; ay += P[256 + t];
    }
    float d = dinv[i];
    float z0 = d * ax + b2[0];
    float z1 = d * ay + b2[1];
    float m = fmaxf(z0, z1);
    float lse = m + logf(expf(z0 - m) + expf(z1 - m));
    ((float2*)out)[i] = make_float2(z0 - lse, z1 - lse);
}

extern "C" void kernel_launch(void* const* d_in, const int* in_sizes, int n_in,
                              void* d_out, int out_size, void* d_ws, size_t ws_size,
                              hipStream_t stream) {
    const float* x  = (const float*)d_in[0];   // [n,2]
    const int*   ei = (const int*)d_in[1];     // [2,e]: row0=src, row1=dst
    const float* W1 = (const float*)d_in[2];   // [2,16]
    const float* b1 = (const float*)d_in[3];   // [16]
    const float* W2 = (const float*)d_in[4];   // [16,2]
    const float* b2 = (const float*)d_in[5];   // [2]
    float* out = (float*)d_out;                // [n,2]

    const int n = in_sizes[0] / 2;             // 100000
    const int e = in_sizes[1] / 2;             // 3200000
    const int* src = ei;
    const int* dst = ei + e;

    const int nbkt = (n + 255) >> 8;           // 391
    int ept = (((e + NTILE - 1) / NTILE) + 3) & ~3;   // 6252

    char* base = (char*)d_ws;
    size_t off = 0;
    auto take = [&](size_t bytes) { char* p = base + off; off += (bytes + 255) & ~(size_t)255; return p; };
    unsigned* sorted  = (unsigned*)take((size_t)nbkt * CAP * 4);          // 14.4 MB
    int*      gcur    = (int*)take((size_t)MAXB * GSTRIDE * 4);           // 32 KB
    float*    partial = (float*)take((size_t)nbkt * NS * 512 * 4);        // 6.4 MB (aliases pdeg)
    int*      pdeg    = (int*)partial;
    float*    dinv    = (float*)take((size_t)n * 4);
    float*    xp      = (float*)take((size_t)n * 8);
    float*    gp      = (float*)take((size_t)n * 8);

    const int gn = (n + BLK - 1) / BLK;
    dim3 gslice(nbkt, NS);

    hipMemsetAsync(gcur, 0, (size_t)MAXB * GSTRIDE * 4, stream);
    k_sort      <<<NTILE, BLK, 0, stream>>>(src, dst, gcur, sorted, e, ept, nbkt);
    k_deg_slice <<<gslice, BLK, 0, stream>>>(sorted, gcur, pdeg);
    k_dinv_merge<<<gn, BLK, 0, stream>>>(pdeg, x, dinv, xp, n);
    k_agg_slice <<<gslice, BLK, 0, stream>>>(sorted, gcur, xp, partial);   // layer 1
    k_mlp_merge <<<gn, BLK, 0, stream>>>(partial, dinv, xp, W1, b1, W2, gp, n);
    k_agg_slice <<<gslice, BLK, 0, stream>>>(sorted, gcur, gp, partial);   // layer 2
    k_final     <<<gn, BLK, 0, stream>>>(partial, dinv, gp, b2, out, n);
}